// Round 18
// baseline (402.783 us; speedup 1.0000x reference)
//
#include <hip/hip_runtime.h>
#include <cstdint>
#include <cstddef>

using u16 = unsigned short;
using u32 = unsigned int;

typedef __bf16 bf16x8 __attribute__((ext_vector_type(8)));
typedef float f32x4 __attribute__((ext_vector_type(4)));

#define AS1 __attribute__((address_space(1)))
#define AS3 __attribute__((address_space(3)))

__device__ __forceinline__ void gload16(const void* g, void* l) {
  __builtin_amdgcn_global_load_lds((const AS1 u32*)g, (AS3 u32*)l, 16, 0, 0);
}

__device__ __forceinline__ u16 bf16bits(float f) {
  u32 u = __float_as_uint(f);
  u32 r = (u + 0x7fffu + ((u >> 16) & 1u)) >> 16;
  return (u16)r;
}

__device__ __forceinline__ float bf16dec(u16 v) {
  return __uint_as_float(((u32)v) << 16);
}

// XCD-chunked bijective block remap (m204), nb-fast so consecutive blocks on
// one XCD share the A-panel (L2-resident).
__device__ __forceinline__ void xcd_tile(int bid, int nwg, int nfast,
                                         int& mb, int& nb) {
  int q = nwg >> 3, r = nwg & 7;
  int xcd = bid & 7, idx = bid >> 3;
  int nid = (xcd < r ? xcd * (q + 1) : r * (q + 1) + (xcd - r) * q) + idx;
  nb = nid % nfast;
  mb = nid / nfast;
}

// ---------------------------------------------------------------------------
// 128x128 bf16 pipelined GEMM core, 8-wave (R10/R13/R14-proven, best measured):
// BK=64, 2 buffers (64KB LDS -> 2 blocks/CU), counted vmcnt, 512 thr =
// 8 waves (2M x 4N), per-wave C = 64x32 (4x2 frags).  16 waves/CU.
// Per iter t: STAGE(t+1 -> buf[(t+1)&1], 4 gloads/thr) -> vmcnt(4) [tile t
// complete, t+1 in flight] -> s_barrier -> ds_read buf[t&1] + 16 MFMA/wave
// -> lgkm(0) -> s_barrier.  Distance-1 prefetch race-free (R9/R10-verified).
// ---------------------------------------------------------------------------
__device__ __forceinline__ void gemm128w8_core(const u16* __restrict__ A,
                                               const u16* __restrict__ Bt,
                                               int K, int mb, int nb,
                                               char* smem, f32x4 (&acc)[4][2]) {
  const int tid = (int)threadIdx.x;
  const int lane = tid & 63;
  const int w = tid >> 6;
  const int wr = w >> 2, wc = w & 3;

  const int srow = w * 16 + (lane >> 3);       // round r adds 8
  const int schk = lane & 7;
  const int gswz = schk ^ (srow & 7);          // same for both rounds (row+8)
  const u16* gA0 = A  + (size_t)(mb * 128 + srow) * K + gswz * 8;
  const u16* gA1 = A  + (size_t)(mb * 128 + srow + 8) * K + gswz * 8;
  const u16* gB0 = Bt + (size_t)(nb * 128 + srow) * K + gswz * 8;
  const u16* gB1 = Bt + (size_t)(nb * 128 + srow + 8) * K + gswz * 8;
  const int lwa = w * 2048;                    // wave-uniform LDS slab base

#pragma unroll
  for (int i = 0; i < 4; ++i)
#pragma unroll
    for (int j = 0; j < 2; ++j)
      acc[i][j] = f32x4{0.f, 0.f, 0.f, 0.f};

  const int rsel = lane & 15;
  const int csel = lane >> 4;
  const int sx = rsel & 7;
  int aoff[2][4], boff[2][2];
#pragma unroll
  for (int kk = 0; kk < 2; ++kk) {
#pragma unroll
    for (int m = 0; m < 4; ++m) {
      int ra = wr * 64 + m * 16 + rsel;
      aoff[kk][m] = ra * 128 + (((kk * 4 + csel) ^ sx) << 4);
    }
#pragma unroll
    for (int n = 0; n < 2; ++n) {
      int rb = wc * 32 + n * 16 + rsel;
      boff[kk][n] = rb * 128 + (((kk * 4 + csel) ^ sx) << 4);
    }
  }

  const int nk = K >> 6;

#define STAGE_W8(kt, b)                                                        \
  {                                                                            \
    char* As_ = smem + (b) * 32768;                                            \
    char* Bs_ = As_ + 16384;                                                   \
    gload16(gA0 + (size_t)(kt) * 64, As_ + lwa);                               \
    gload16(gA1 + (size_t)(kt) * 64, As_ + lwa + 1024);                        \
    gload16(gB0 + (size_t)(kt) * 64, Bs_ + lwa);                               \
    gload16(gB1 + (size_t)(kt) * 64, Bs_ + lwa + 1024);                        \
  }

  STAGE_W8(0, 0);

  for (int kt = 0; kt < nk; ++kt) {
    if (kt + 1 < nk) {
      STAGE_W8(kt + 1, (kt + 1) & 1);
      asm volatile("s_waitcnt vmcnt(4)" ::: "memory");
    } else {
      asm volatile("s_waitcnt vmcnt(0)" ::: "memory");
    }
    __builtin_amdgcn_s_barrier();

    char* As = smem + (kt & 1) * 32768;
    char* Bs = As + 16384;
#pragma unroll
    for (int kk = 0; kk < 2; ++kk) {
      bf16x8 af[4], bf[2];
#pragma unroll
      for (int m = 0; m < 4; ++m) af[m] = *(const bf16x8*)(As + aoff[kk][m]);
#pragma unroll
      for (int n = 0; n < 2; ++n) bf[n] = *(const bf16x8*)(Bs + boff[kk][n]);
      __builtin_amdgcn_s_setprio(1);
#pragma unroll
      for (int m = 0; m < 4; ++m)
#pragma unroll
        for (int n = 0; n < 2; ++n)
          acc[m][n] = __builtin_amdgcn_mfma_f32_16x16x32_bf16(af[m], bf[n], acc[m][n], 0, 0, 0);
      __builtin_amdgcn_s_setprio(0);
    }
    asm volatile("s_waitcnt lgkmcnt(0)" ::: "memory");
    __builtin_amdgcn_s_barrier();
  }
#undef STAGE_W8
}

// ---------------------------------------------------------------------------
// ln1_prep: fused LN1(+roll+window gather), weight transposes + bias table,
// and (fast path only, blocks >= 20224) the LN2-fold vectors:
//   Gv[n] = sum_k n2g[k]*fc1_w[k,n],  Cv[n] = sum_k n2b[k]*fc1_w[k,n] + fc1_b[n]
// foldg=1 folds n2g into wf1t (fast path); 0 keeps R14 behavior (fallback).
// ---------------------------------------------------------------------------
__global__ __launch_bounds__(256) void ln1_prep(
    const float* __restrict__ x, const float* __restrict__ g,
    const float* __restrict__ b, u16* __restrict__ xw,
    const float* __restrict__ qkv_w, const float* __restrict__ proj_w,
    const float* __restrict__ fc1_w, const float* __restrict__ fc2_w,
    const float* __restrict__ rpb,
    const float* __restrict__ n2g, const float* __restrict__ n2b,
    const float* __restrict__ fc1_b,
    u16* __restrict__ wqt, u16* __restrict__ wpt,
    u16* __restrict__ wf1t, u16* __restrict__ wf2t,
    float* __restrict__ bt, float* __restrict__ Gv, float* __restrict__ Cv,
    int foldg) {
  if (blockIdx.x < 12544) {
    const int lane = threadIdx.x & 63;
    const int w = threadIdx.x >> 6;
    const int row = blockIdx.x * 4 + w;
    const int win = row / 49, tok = row - win * 49;
    const int bimg = win >> 6, wloc = win & 63, wi = wloc >> 3, wj = wloc & 7;
    const int r = tok / 7, cc = tok - r * 7;
    const int ho = (wi * 7 + r + 3) % 56;
    const int wo = (wj * 7 + cc + 3) % 56;
    const float* src = x + ((size_t)bimg * 3136 + ho * 56 + wo) * 384;
    float v[6]; float s = 0.f, s2 = 0.f;
#pragma unroll
    for (int i = 0; i < 6; ++i) { float t = src[lane + i * 64]; v[i] = t; s += t; s2 += t * t; }
#pragma unroll
    for (int o = 1; o < 64; o <<= 1) { s += __shfl_xor(s, o); s2 += __shfl_xor(s2, o); }
    float mu = s * (1.f / 384.f);
    float rs = rsqrtf(s2 * (1.f / 384.f) - mu * mu + 1e-5f);
    u16* dst = xw + (size_t)row * 384;
#pragma unroll
    for (int i = 0; i < 6; ++i) {
      int c = lane + i * 64;
      dst[c] = bf16bits((v[i] - mu) * rs * g[c] + b[c]);
    }
    return;
  }
  if (blockIdx.x >= 20224) {                // LN2-fold vectors (fast path only)
    int n = (blockIdx.x - 20224) * 256 + threadIdx.x;
    if (n < 1536) {
      float gw = 0.f, bw = 0.f;
      for (int k = 0; k < 384; ++k) {
        float wv = fc1_w[(size_t)k * 1536 + n];
        gw += n2g[k] * wv;
        bw += n2b[k] * wv;
      }
      Gv[n] = gw;
      Cv[n] = bw + fc1_b[n];
    }
    return;
  }
  int idx = (blockIdx.x - 12544) * 256 + threadIdx.x;
  if (idx < 442368) {                       // wqt [1152][384], q cols scaled
    int n = idx / 384, k = idx - n * 384;
    float wv = qkv_w[(size_t)k * 1152 + n];
    if (n < 384) wv *= 0.17677669529663687f;
    wqt[idx] = bf16bits(wv);
    return;
  }
  idx -= 442368;
  if (idx < 147456) {                       // wpt [384][384]
    int n = idx / 384, k = idx - n * 384;
    wpt[idx] = bf16bits(proj_w[(size_t)k * 384 + n]);
    return;
  }
  idx -= 147456;
  if (idx < 589824) {                       // wf1t [1536][384] (g-folded if fast)
    int n = idx / 384, k = idx - n * 384;
    float wv = fc1_w[(size_t)k * 1536 + n];
    if (foldg) wv *= n2g[k];
    wf1t[idx] = bf16bits(wv);
    return;
  }
  idx -= 589824;
  if (idx < 589824) {                       // wf2t [384][1536]
    int n = idx / 1536, k = idx - n * 1536;
    wf2t[idx] = bf16bits(fc2_w[(size_t)k * 384 + n]);
    return;
  }
  idx -= 589824;
  if (idx >= 196608) return;                // bt [4][12][64][64]
  int col = idx & 63, row = (idx >> 6) & 63;
  int rest = idx >> 12;
  int h = rest % 12, cls = rest / 12;
  float v;
  if (row >= 49 || col >= 49) {
    v = -1e30f;
  } else {
    int qr = row / 7, qc = row - qr * 7;
    int kr = col / 7, kc = col - kr * 7;
    v = rpb[((qr - kr + 6) * 13 + (qc - kc + 6)) * 12 + h];
    bool wi7 = (cls & 2) != 0, wj7 = (cls & 1) != 0;
    int idq = (wi7 ? (qr < 4 ? 3 : 6) : 0) + (wj7 ? (qc < 4 ? 1 : 2) : 0);
    int idk = (wi7 ? (kr < 4 ? 3 : 6) : 0) + (wj7 ? (kc < 4 ? 1 : 2) : 0);
    if (idq != idk) v += -100.f;
  }
  bt[idx] = v;
}

// rowstat (fast path): per-row LN2 stats from x2b.  rs[row], rsmu[row]=rs*mu.
__global__ __launch_bounds__(256) void rowstat(const u16* __restrict__ x2b,
                                               float* __restrict__ rs,
                                               float* __restrict__ rsmu) {
  const int lane = threadIdx.x & 63;
  const int w = threadIdx.x >> 6;
  const int row = blockIdx.x * 4 + w;
  const u16* src = x2b + (size_t)row * 384;
  float s = 0.f, s2 = 0.f;
#pragma unroll
  for (int i = 0; i < 6; ++i) { float t = bf16dec(src[lane + i * 64]); s += t; s2 += t * t; }
#pragma unroll
  for (int o = 1; o < 64; o <<= 1) { s += __shfl_xor(s, o); s2 += __shfl_xor(s2, o); }
  if (lane == 0) {
    float mu = s * (1.f / 384.f);
    float rv = rsqrtf(s2 * (1.f / 384.f) - mu * mu + 1e-5f);
    rs[row] = rv;
    rsmu[row] = rv * mu;
  }
}

// LN2 (f32 input variant, R14 fallback): reads x2 f32 in d_out, writes bf16 h2
__global__ __launch_bounds__(256) void ln2_f32(const float* __restrict__ xin,
                                               const float* __restrict__ g,
                                               const float* __restrict__ b,
                                               u16* __restrict__ h2) {
  const int lane = threadIdx.x & 63;
  const int w = threadIdx.x >> 6;
  const int row = blockIdx.x * 4 + w;
  const float* src = xin + (size_t)row * 384;
  float v[6]; float s = 0.f, s2 = 0.f;
#pragma unroll
  for (int i = 0; i < 6; ++i) { float t = src[lane + i * 64]; v[i] = t; s += t; s2 += t * t; }
#pragma unroll
  for (int o = 1; o < 64; o <<= 1) { s += __shfl_xor(s, o); s2 += __shfl_xor(s2, o); }
  float mu = s * (1.f / 384.f);
  float rsv = rsqrtf(s2 * (1.f / 384.f) - mu * mu + 1e-5f);
  u16* dst = h2 + (size_t)row * 384;
#pragma unroll
  for (int i = 0; i < 6; ++i) {
    int c = lane + i * 64;
    dst[c] = bf16bits((v[i] - mu) * rsv * g[c] + b[c]);
  }
}

// ---------------------------------------------------------------------------
// QKV GEMM (128w8 core): [50176,384]x[384,1152] + bias -> [50176][1152].
// ---------------------------------------------------------------------------
__global__ __launch_bounds__(512, 4) void qkv_gemm(const u16* __restrict__ A,
                                                   const u16* __restrict__ Bt,
                                                   const float* __restrict__ bias,
                                                   u16* __restrict__ qkvb) {
  __shared__ char smem[65536];
  int mb, nb;
  xcd_tile(blockIdx.x, 3528, 9, mb, nb);
  f32x4 acc[4][2];
  gemm128w8_core(A, Bt, 384, mb, nb, smem, acc);
  const int lane = threadIdx.x & 63, w = threadIdx.x >> 6;
  const int wr = w >> 2, wc = w & 3;
  const int r0 = mb * 128 + wr * 64 + ((lane >> 4) << 2);
  const int c0 = nb * 128 + wc * 32 + (lane & 15);
  const float qs = (nb < 3) ? 0.17677669529663687f : 1.0f;
  float bj[2];
#pragma unroll
  for (int n = 0; n < 2; ++n) bj[n] = bias[c0 + n * 16] * qs;
#pragma unroll
  for (int m = 0; m < 4; ++m)
#pragma unroll
    for (int e = 0; e < 4; ++e) {
      int row = r0 + m * 16 + e;
      u16* dst = qkvb + (size_t)row * 1152 + c0;
#pragma unroll
      for (int n = 0; n < 2; ++n)
        dst[n * 16] = bf16bits(acc[m][n][e] + bj[n]);
    }
}

// ---------------------------------------------------------------------------
// Attention (R3-proven): 128 threads = 2 independent waves, one (win,head) each.
// ---------------------------------------------------------------------------
__global__ __launch_bounds__(128, 3) void attn2(const u16* __restrict__ qkvb,
                                                const float* __restrict__ bt,
                                                u16* __restrict__ ob) {
  __shared__ char smem[26112];
  const int wv = threadIdx.x >> 6, lane = threadIdx.x & 63;
  char* vts = smem + wv * 13056;          // [32 d][136B]
  char* ps  = smem + wv * 13056 + 4352;   // [64 q][136B]
  const int p = blockIdx.x * 2 + wv;
  const int win = p / 12, head = p - win * 12;
  const int wloc = win & 63, wi = wloc >> 3, wj = wloc & 7;
  const int cls = ((wi == 7) ? 2 : 0) + ((wj == 7) ? 1 : 0);

#pragma unroll
  for (int i = 0; i < 17; ++i) ((u32*)vts)[lane + i * 64] = 0;

  const u16* qg = qkvb + (size_t)win * 49 * 1152 + head * 32;
  const u16* kg = qg + 384;
  const u16* vg = qg + 768;
#pragma unroll
  for (int it = 0; it < 4; ++it) {
    int c = lane + it * 64;
    if (c < 196) {
      int tok = c >> 2, d0 = (c & 3) * 8;
      union { uint4 v; u16 h[8]; } u;
      u.v = *(const uint4*)(vg + (size_t)tok * 1152 + d0);
#pragma unroll
      for (int jj = 0; jj < 8; ++jj)
        *(u16*)(vts + (d0 + jj) * 136 + tok * 2) = u.h[jj];
    }
  }

  const int rsel = lane & 15;
  const int ksub = lane >> 4;
  bf16x8 aq[4], bk[4];
#pragma unroll
  for (int t = 0; t < 4; ++t) {
    int row = t * 16 + rsel;
    union { uint4 u; bf16x8 v; } rq, rk;
    if (row < 49) {
      rq.u = *(const uint4*)(qg + (size_t)row * 1152 + ksub * 8);
      rk.u = *(const uint4*)(kg + (size_t)row * 1152 + ksub * 8);
    } else {
      rq.u = uint4{0, 0, 0, 0};
      rk.u = uint4{0, 0, 0, 0};
    }
    aq[t] = rq.v; bk[t] = rk.v;
  }

  f32x4 s[4][4];
#pragma unroll
  for (int i = 0; i < 4; ++i)
#pragma unroll
    for (int j = 0; j < 4; ++j) s[i][j] = f32x4{0.f, 0.f, 0.f, 0.f};
#pragma unroll
  for (int i = 0; i < 4; ++i)
#pragma unroll
    for (int j = 0; j < 4; ++j)
      s[i][j] = __builtin_amdgcn_mfma_f32_16x16x32_bf16(aq[i], bk[j], s[i][j], 0, 0, 0);

  const float* tb = bt + ((size_t)(cls * 12 + head) << 12);
  const int rowsub = ksub << 2;
#pragma unroll
  for (int i = 0; i < 4; ++i) {
    float bl[4][4];
#pragma unroll
    for (int e = 0; e < 4; ++e) {
      int row = i * 16 + rowsub + e;
#pragma unroll
      for (int j = 0; j < 4; ++j) bl[e][j] = tb[row * 64 + j * 16 + rsel];
    }
#pragma unroll
    for (int e = 0; e < 4; ++e) {
      int row = i * 16 + rowsub + e;
      float v[4];
#pragma unroll
      for (int j = 0; j < 4; ++j) v[j] = s[i][j][e] + bl[e][j];
      float m = fmaxf(fmaxf(v[0], v[1]), fmaxf(v[2], v[3]));
#pragma unroll
      for (int o = 1; o < 16; o <<= 1) m = fmaxf(m, __shfl_xor(m, o));
      float pr[4]; float sum = 0.f;
#pragma unroll
      for (int j = 0; j < 4; ++j) { pr[j] = __expf(v[j] - m); sum += pr[j]; }
#pragma unroll
      for (int o = 1; o < 16; o <<= 1) sum += __shfl_xor(sum, o);
      float inv = 1.f / sum;
#pragma unroll
      for (int j = 0; j < 4; ++j)
        *(u16*)(ps + row * 136 + (j * 16 + rsel) * 2) = bf16bits(pr[j] * inv);
    }
  }

  f32x4 o[4][2];
#pragma unroll
  for (int i = 0; i < 4; ++i)
#pragma unroll
    for (int j = 0; j < 2; ++j) o[i][j] = f32x4{0.f, 0.f, 0.f, 0.f};
#pragma unroll
  for (int kk = 0; kk < 2; ++kk) {
    bf16x8 ap[4], bv[2];
#pragma unroll
    for (int t = 0; t < 4; ++t)
      ap[t] = *(const bf16x8*)(ps + (t * 16 + rsel) * 136 + kk * 64 + ksub * 16);
#pragma unroll
    for (int t = 0; t < 2; ++t)
      bv[t] = *(const bf16x8*)(vts + (t * 16 + rsel) * 136 + kk * 64 + ksub * 16);
#pragma unroll
    for (int i = 0; i < 4; ++i)
#pragma unroll
      for (int j = 0; j < 2; ++j)
        o[i][j] = __builtin_amdgcn_mfma_f32_16x16x32_bf16(ap[i], bv[j], o[i][j], 0, 0, 0);
  }

  u16* obase = ob + (size_t)win * 49 * 384 + head * 32;
#pragma unroll
  for (int i = 0; i < 4; ++i)
#pragma unroll
    for (int j = 0; j < 2; ++j)
#pragma unroll
      for (int e = 0; e < 4; ++e) {
        int tok = i * 16 + rowsub + e;
        if (tok < 49)
          obase[(size_t)tok * 384 + j * 16 + rsel] = bf16bits(o[i][j][e]);
      }
}

// ---------------------------------------------------------------------------
// proj GEMM, f32-residual variant (R14 fallback).
// ---------------------------------------------------------------------------
__global__ __launch_bounds__(512, 4) void proj_f32(const u16* __restrict__ A,
                                                   const u16* __restrict__ Bt,
                                                   const float* __restrict__ bias,
                                                   const float* __restrict__ xres,
                                                   float* __restrict__ out) {
  __shared__ char smem[65536];
  int mb, nb;
  xcd_tile(blockIdx.x, 1176, 3, mb, nb);
  f32x4 acc[4][2];
  gemm128w8_core(A, Bt, 384, mb, nb, smem, acc);
  const int lane = threadIdx.x & 63, w = threadIdx.x >> 6;
  const int wr = w >> 2, wc = w & 3;
  const int r0 = mb * 128 + wr * 64 + ((lane >> 4) << 2);
  const int c0 = nb * 128 + wc * 32 + (lane & 15);
  float bj[2];
#pragma unroll
  for (int n = 0; n < 2; ++n) bj[n] = bias[c0 + n * 16];
#pragma unroll
  for (int m = 0; m < 4; ++m)
#pragma unroll
    for (int e = 0; e < 4; ++e) {
      int row = r0 + m * 16 + e;
      int wn = row / 49, tok = row - wn * 49;
      int bimg = wn >> 6, wloc = wn & 63, wi = wloc >> 3, wj = wloc & 7;
      int r = tok / 7, cc = tok - r * 7;
      int t1 = wi * 7 + r + 3;  int ho = t1 >= 56 ? t1 - 56 : t1;
      int t2 = wj * 7 + cc + 3; int wo = t2 >= 56 ? t2 - 56 : t2;
      size_t gbase = ((size_t)bimg * 3136 + ho * 56 + wo) * 384 + c0;
#pragma unroll
      for (int n = 0; n < 2; ++n) {
        size_t gi = gbase + n * 16;
        out[gi] = acc[m][n][e] + bj[n] + xres[gi];
      }
    }
}

// proj GEMM, bf16-residual variant (R12/R17-validated): -> x2b bf16.
__global__ __launch_bounds__(512, 4) void proj_bf16(const u16* __restrict__ A,
                                                    const u16* __restrict__ Bt,
                                                    const float* __restrict__ bias,
                                                    const float* __restrict__ xres,
                                                    u16* __restrict__ x2b) {
  __shared__ char smem[65536];
  int mb, nb;
  xcd_tile(blockIdx.x, 1176, 3, mb, nb);
  f32x4 acc[4][2];
  gemm128w8_core(A, Bt, 384, mb, nb, smem, acc);
  const int lane = threadIdx.x & 63, w = threadIdx.x >> 6;
  const int wr = w >> 2, wc = w & 3;
  const int r0 = mb * 128 + wr * 64 + ((lane >> 4) << 2);
  const int c0 = nb * 128 + wc * 32 + (lane & 15);
  float bj[2];
#pragma unroll
  for (int n = 0; n < 2; ++n) bj[n] = bias[c0 + n * 16];
#pragma unroll
  for (int m = 0; m < 4; ++m)
#pragma unroll
    for (int e = 0; e < 4; ++e) {
      int row = r0 + m * 16 + e;
      int wn = row / 49, tok = row - wn * 49;
      int bimg = wn >> 6, wloc = wn & 63, wi = wloc >> 3, wj = wloc & 7;
      int r = tok / 7, cc = tok - r * 7;
      int t1 = wi * 7 + r + 3;  int ho = t1 >= 56 ? t1 - 56 : t1;
      int t2 = wj * 7 + cc + 3; int wo = t2 >= 56 ? t2 - 56 : t2;
      size_t gbase = ((size_t)bimg * 3136 + ho * 56 + wo) * 384 + c0;
#pragma unroll
      for (int n = 0; n < 2; ++n) {
        size_t gi = gbase + n * 16;
        x2b[gi] = bf16bits(acc[m][n][e] + bj[n] + xres[gi]);
      }
    }
}

// fc1 plain variant (fallback): A = h2, epilogue bias+GELU.
__global__ __launch_bounds__(512, 4) void fc1_plain(const u16* __restrict__ A,
                                                    const u16* __restrict__ Bt,
                                                    const float* __restrict__ bias,
                                                    u16* __restrict__ h3) {
  __shared__ char smem[65536];
  int mb, nb;
  xcd_tile(blockIdx.x, 4704, 12, mb, nb);
  f32x4 acc[4][2];
  gemm128w8_core(A, Bt, 384, mb, nb, smem, acc);
  const int lane = threadIdx.x & 63, w = threadIdx.x >> 6;
  const int wr = w >> 2, wc = w & 3;
  const int r0 = mb * 128 + wr * 64 + ((lane >> 4) << 2);
  const int c0 = nb * 128 + wc * 32 + (lane & 15);
  float bj[2];
#pragma unroll
  for (int n = 0; n < 2; ++n) bj[n] = bias[c0 + n * 16];
#pragma unroll
  for (int m = 0; m < 4; ++m)
#pragma unroll
    for (int e = 0; e < 4; ++e) {
      int row = r0 + m * 16 + e;
      u16* dst = h3 + (size_t)row * 1536 + c0;
#pragma unroll
      for (int n = 0; n < 2; ++n) {
        float v = acc[m][n][e] + bj[n];
        float gl = 0.5f * v * (1.f + erff(v * 0.70710678118654752f));
        dst[n * 16] = bf16bits(gl);
      }
    }
}

// fc1 LN-folded variant (fast): A = x2b (raw residual), epilogue applies
// v = rs[row]*acc - rsmu[row]*Gv[col] + Cv[col], then GELU.
__global__ __launch_bounds__(512, 4) void fc1_fused(const u16* __restrict__ A,
                                                    const u16* __restrict__ Bt,
                                                    const float* __restrict__ rs,
                                                    const float* __restrict__ rsmu,
                                                    const float* __restrict__ Gv,
                                                    const float* __restrict__ Cv,
                                                    u16* __restrict__ h3) {
  __shared__ char smem[65536];
  int mb, nb;
  xcd_tile(blockIdx.x, 4704, 12, mb, nb);
  f32x4 acc[4][2];
  gemm128w8_core(A, Bt, 384, mb, nb, smem, acc);
  const int lane = threadIdx.x & 63, w = threadIdx.x >> 6;
  const int wr = w >> 2, wc = w & 3;
  const int r0 = mb * 128 + wr * 64 + ((lane >> 4) << 2);
  const int c0 = nb * 128 + wc * 32 + (lane & 15);
  float Gj[2], Cj[2];
#pragma unroll
  for (int n = 0; n < 2; ++n) { Gj[n] = Gv[c0 + n * 16]; Cj[n] = Cv[c0 + n * 16]; }
#pragma unroll
  for (int m = 0; m < 4; ++m)
#pragma unroll
    for (int e = 0; e < 4; ++e) {
      int row = r0 + m * 16 + e;
      float rv = rs[row], rmv = rsmu[row];
      u16* dst = h3 + (size_t)row * 1536 + c0;
#pragma unroll
      for (int n = 0; n < 2; ++n) {
        float v = rv * acc[m][n][e] - rmv * Gj[n] + Cj[n];
        float gl = 0.5f * v * (1.f + erff(v * 0.70710678118654752f));
        dst[n * 16] = bf16bits(gl);
      }
    }
}

// fc2 RMW variant (fallback): out += mlp (out pre-holds x2 f32).
__global__ __launch_bounds__(512, 4) void fc2_rmw(const u16* __restrict__ A,
                                                  const u16* __restrict__ Bt,
                                                  const float* __restrict__ bias,
                                                  float* __restrict__ out) {
  __shared__ char smem[65536];
  int mb, nb;
  xcd_tile(blockIdx.x, 1176, 3, mb, nb);
  f32x4 acc[4][2];
  gemm128w8_core(A, Bt, 1536, mb, nb, smem, acc);
  const int lane = threadIdx.x & 63, w = threadIdx.x >> 6;
  const int wr = w >> 2, wc = w & 3;
  const int r0 = mb * 128 + wr * 64 + ((lane >> 4) << 2);
  const int c0 = nb * 128 + wc * 32 + (lane & 15);
  float bj[2];
#pragma unroll
  for (int n = 0; n < 2; ++n) bj[n] = bias[c0 + n * 16];
#pragma unroll
  for (int m = 0; m < 4; ++m)
#pragma unroll
    for (int e = 0; e < 4; ++e) {
      int row = r0 + m * 16 + e;
      float* dst = out + (size_t)row * 384 + c0;
#pragma unroll
      for (int n = 0; n < 2; ++n)
        dst[n * 16] += acc[m][n][e] + bj[n];
    }
}

// fc2 write-once variant (fast): out = bf16dec(x2b) + mlp.
__global__ __launch_bounds__(512, 4) void fc2_once(const u16* __restrict__ A,
                                                   const u16* __restrict__ Bt,
                                                   const float* __restrict__ bias,
                                                   const u16* __restrict__ x2b,
                                                   float* __restrict__ out) {
  __shared__ char smem[65536];
  int mb, nb;
  xcd_tile(blockIdx.x, 1176, 3, mb, nb);
  f32x4 acc[4][2];
  gemm128w8_core(A, Bt, 1536, mb, nb, smem, acc);
  const int lane = threadIdx.x & 63, w = threadIdx.x >> 6;
  const int wr = w >> 2, wc = w & 3;
  const int r0 = mb * 128 + wr * 64 + ((lane >> 4) << 2);
  const int c0 = nb * 128 + wc * 32 + (lane & 15);
  float bj[2];
#pragma unroll
  for (int n = 0; n < 2; ++n) bj[n] = bias[c0 + n * 16];
#pragma unroll
  for (int m = 0; m < 4; ++m)
#pragma unroll
    for (int e = 0; e < 4; ++e) {
      size_t row = (size_t)(r0 + m * 16 + e);
#pragma unroll
      for (int n = 0; n < 2; ++n) {
        size_t gi = row * 384 + c0 + n * 16;
        out[gi] = bf16dec(x2b[gi]) + acc[m][n][e] + bj[n];
      }
    }
}

// ---------------------------------------------------------------------------
extern "C" void kernel_launch(void* const* d_in, const int* in_sizes, int n_in,
                              void* d_out, int out_size, void* d_ws, size_t ws_size,
                              hipStream_t stream) {
  const float* x      = (const float*)d_in[0];
  const float* n1g    = (const float*)d_in[1];
  const float* n1b    = (const float*)d_in[2];
  const float* qkv_w  = (const float*)d_in[3];
  const float* qkv_b  = (const float*)d_in[4];
  const float* rpb    = (const float*)d_in[5];
  const float* proj_w = (const float*)d_in[6];
  const float* proj_b = (const float*)d_in[7];
  const float* n2g    = (const float*)d_in[8];
  const float* n2b    = (const float*)d_in[9];
  const float* fc1_w  = (const float*)d_in[10];
  const float* fc1_b  = (const float*)d_in[11];
  const float* fc2_w  = (const float*)d_in[12];
  const float* fc2_b  = (const float*)d_in[13];
  float* out = (float*)d_out;

  char* ws = (char*)d_ws;
  const size_t S = (size_t)50176 * 384 * 2;   // 38.5 MB
  const size_t WB = (size_t)(442368 + 147456 + 589824 + 589824) * 2; // weights
  const bool fast = ws_size >= 7 * S + WB + 786432 + (size_t)8 * 1024 * 1024;

  u16* xw = (u16*)ws;                         // [0,S): LN1 out / attn out

  if (fast) {
    // FAST layout: qkvb [S,4S); post-attn x2b [S,2S); h3 [3S,7S);
    // bt [7S); weights; stats (rs, rsmu, Gv, Cv) after.
    u16* qkvb = (u16*)(ws + S);
    u16* x2b  = (u16*)(ws + S);
    u16* h3   = (u16*)(ws + 3 * S);
    float* bias_t = (float*)(ws + 7 * S);
    u16* wqt  = (u16*)(ws + 7 * S + 786432);
    u16* wpt  = wqt  + 1152 * 384;
    u16* wf1t = wpt  + 384 * 384;
    u16* wf2t = wf1t + 1536 * 384;
    float* rs_a   = (float*)(wf2t + 1536 * 384);
    float* rsmu_a = rs_a + 50176;
    float* Gv     = rsmu_a + 50176;
    float* Cv     = Gv + 1536;

    ln1_prep<<<20230, 256, 0, stream>>>(x, n1g, n1b, xw,
                                        qkv_w, proj_w, fc1_w, fc2_w, rpb,
                                        n2g, n2b, fc1_b,
                                        wqt, wpt, wf1t, wf2t, bias_t, Gv, Cv, 1);
    qkv_gemm<<<3528, 512, 0, stream>>>(xw, wqt, qkv_b, qkvb);
    attn2<<<6144, 128, 0, stream>>>(qkvb, bias_t, xw);
    proj_bf16<<<1176, 512, 0, stream>>>(xw, wpt, proj_b, x, x2b);
    rowstat<<<12544, 256, 0, stream>>>(x2b, rs_a, rsmu_a);
    fc1_fused<<<4704, 512, 0, stream>>>(x2b, wf1t, rs_a, rsmu_a, Gv, Cv, h3);
    fc2_once<<<1176, 512, 0, stream>>>(h3, wf2t, fc2_b, x2b, out);
  } else {
    // FALLBACK = R14 layout (f32 residual in d_out), foldg=0, no G/C blocks.
    u16* qkvb = (u16*)(ws + S);
    u16* h2   = (u16*)(ws + 4 * S);
    u16* h3   = (u16*)ws;                     // aliases xw+qkvb (dead)
    float* bias_t = (float*)(ws + 4 * S);     // aliases h2 (free until ln2)
    u16* wqt  = (u16*)(ws + 5 * S);
    u16* wpt  = wqt  + 1152 * 384;
    u16* wf1t = wpt  + 384 * 384;
    u16* wf2t = wf1t + 1536 * 384;

    ln1_prep<<<20224, 256, 0, stream>>>(x, n1g, n1b, xw,
                                        qkv_w, proj_w, fc1_w, fc2_w, rpb,
                                        n2g, n2b, fc1_b,
                                        wqt, wpt, wf1t, wf2t, bias_t,
                                        bias_t, bias_t, 0);
    qkv_gemm<<<3528, 512, 0, stream>>>(xw, wqt, qkv_b, qkvb);
    attn2<<<6144, 128, 0, stream>>>(qkvb, bias_t, xw);
    proj_f32<<<1176, 512, 0, stream>>>(xw, wpt, proj_b, x, out);
    ln2_f32<<<12544, 256, 0, stream>>>(out, n2g, n2b, h2);
    fc1_plain<<<4704, 512, 0, stream>>>(h2, wf1t, fc1_b, h3);
    fc2_rmw<<<1176, 512, 0, stream>>>(h3, wf2t, fc2_b, out);
  }
}

// Round 19
// 382.123 us; speedup vs baseline: 1.0541x; 1.0541x over previous
//
#include <hip/hip_runtime.h>
#include <cstdint>
#include <cstddef>

using u16 = unsigned short;
using u32 = unsigned int;

typedef __bf16 bf16x8 __attribute__((ext_vector_type(8)));
typedef float f32x4 __attribute__((ext_vector_type(4)));

#define AS1 __attribute__((address_space(1)))
#define AS3 __attribute__((address_space(3)))

__device__ __forceinline__ void gload16(const void* g, void* l) {
  __builtin_amdgcn_global_load_lds((const AS1 u32*)g, (AS3 u32*)l, 16, 0, 0);
}

__device__ __forceinline__ u16 bf16bits(float f) {
  u32 u = __float_as_uint(f);
  u32 r = (u + 0x7fffu + ((u >> 16) & 1u)) >> 16;
  return (u16)r;
}

__device__ __forceinline__ float bf16dec(u16 v) {
  return __uint_as_float(((u32)v) << 16);
}

// XCD-chunked bijective block remap (m204), nb-fast so consecutive blocks on
// one XCD share the A-panel (L2-resident).
__device__ __forceinline__ void xcd_tile(int bid, int nwg, int nfast,
                                         int& mb, int& nb) {
  int q = nwg >> 3, r = nwg & 7;
  int xcd = bid & 7, idx = bid >> 3;
  int nid = (xcd < r ? xcd * (q + 1) : r * (q + 1) + (xcd - r) * q) + idx;
  nb = nid % nfast;
  mb = nid / nfast;
}

// ---------------------------------------------------------------------------
// 128x128 bf16 pipelined GEMM core, 8-wave (R10/R13/R14-proven, best measured):
// BK=64, 2 buffers (64KB LDS -> 2 blocks/CU), counted vmcnt, 512 thr =
// 8 waves (2M x 4N), per-wave C = 64x32 (4x2 frags).  16 waves/CU.
// Per iter t: STAGE(t+1 -> buf[(t+1)&1], 4 gloads/thr) -> vmcnt(4) [tile t
// complete, t+1 in flight] -> s_barrier -> ds_read buf[t&1] + 16 MFMA/wave
// -> lgkm(0) -> s_barrier.  Distance-1 prefetch race-free (R9/R10-verified).
// ---------------------------------------------------------------------------
__device__ __forceinline__ void gemm128w8_core(const u16* __restrict__ A,
                                               const u16* __restrict__ Bt,
                                               int K, int mb, int nb,
                                               char* smem, f32x4 (&acc)[4][2]) {
  const int tid = (int)threadIdx.x;
  const int lane = tid & 63;
  const int w = tid >> 6;
  const int wr = w >> 2, wc = w & 3;

  const int srow = w * 16 + (lane >> 3);       // round r adds 8
  const int schk = lane & 7;
  const int gswz = schk ^ (srow & 7);          // same for both rounds (row+8)
  const u16* gA0 = A  + (size_t)(mb * 128 + srow) * K + gswz * 8;
  const u16* gA1 = A  + (size_t)(mb * 128 + srow + 8) * K + gswz * 8;
  const u16* gB0 = Bt + (size_t)(nb * 128 + srow) * K + gswz * 8;
  const u16* gB1 = Bt + (size_t)(nb * 128 + srow + 8) * K + gswz * 8;
  const int lwa = w * 2048;                    // wave-uniform LDS slab base

#pragma unroll
  for (int i = 0; i < 4; ++i)
#pragma unroll
    for (int j = 0; j < 2; ++j)
      acc[i][j] = f32x4{0.f, 0.f, 0.f, 0.f};

  const int rsel = lane & 15;
  const int csel = lane >> 4;
  const int sx = rsel & 7;
  int aoff[2][4], boff[2][2];
#pragma unroll
  for (int kk = 0; kk < 2; ++kk) {
#pragma unroll
    for (int m = 0; m < 4; ++m) {
      int ra = wr * 64 + m * 16 + rsel;
      aoff[kk][m] = ra * 128 + (((kk * 4 + csel) ^ sx) << 4);
    }
#pragma unroll
    for (int n = 0; n < 2; ++n) {
      int rb = wc * 32 + n * 16 + rsel;
      boff[kk][n] = rb * 128 + (((kk * 4 + csel) ^ sx) << 4);
    }
  }

  const int nk = K >> 6;

#define STAGE_W8(kt, b)                                                        \
  {                                                                            \
    char* As_ = smem + (b) * 32768;                                            \
    char* Bs_ = As_ + 16384;                                                   \
    gload16(gA0 + (size_t)(kt) * 64, As_ + lwa);                               \
    gload16(gA1 + (size_t)(kt) * 64, As_ + lwa + 1024);                        \
    gload16(gB0 + (size_t)(kt) * 64, Bs_ + lwa);                               \
    gload16(gB1 + (size_t)(kt) * 64, Bs_ + lwa + 1024);                        \
  }

  STAGE_W8(0, 0);

  for (int kt = 0; kt < nk; ++kt) {
    if (kt + 1 < nk) {
      STAGE_W8(kt + 1, (kt + 1) & 1);
      asm volatile("s_waitcnt vmcnt(4)" ::: "memory");
    } else {
      asm volatile("s_waitcnt vmcnt(0)" ::: "memory");
    }
    __builtin_amdgcn_s_barrier();

    char* As = smem + (kt & 1) * 32768;
    char* Bs = As + 16384;
#pragma unroll
    for (int kk = 0; kk < 2; ++kk) {
      bf16x8 af[4], bf[2];
#pragma unroll
      for (int m = 0; m < 4; ++m) af[m] = *(const bf16x8*)(As + aoff[kk][m]);
#pragma unroll
      for (int n = 0; n < 2; ++n) bf[n] = *(const bf16x8*)(Bs + boff[kk][n]);
      __builtin_amdgcn_s_setprio(1);
#pragma unroll
      for (int m = 0; m < 4; ++m)
#pragma unroll
        for (int n = 0; n < 2; ++n)
          acc[m][n] = __builtin_amdgcn_mfma_f32_16x16x32_bf16(af[m], bf[n], acc[m][n], 0, 0, 0);
      __builtin_amdgcn_s_setprio(0);
    }
    asm volatile("s_waitcnt lgkmcnt(0)" ::: "memory");
    __builtin_amdgcn_s_barrier();
  }
#undef STAGE_W8
}

// ---------------------------------------------------------------------------
// ln1_prep: fused LN1(+roll+window gather) AND weight transposes + bias table.
// Blocks [0,12544): ln1 rows.  Blocks [12544,20224): prep.
// q-scale 1/sqrt(32) folded into wqt columns < 384.
// ---------------------------------------------------------------------------
__global__ __launch_bounds__(256) void ln1_prep(
    const float* __restrict__ x, const float* __restrict__ g,
    const float* __restrict__ b, u16* __restrict__ xw,
    const float* __restrict__ qkv_w, const float* __restrict__ proj_w,
    const float* __restrict__ fc1_w, const float* __restrict__ fc2_w,
    const float* __restrict__ rpb,
    u16* __restrict__ wqt, u16* __restrict__ wpt,
    u16* __restrict__ wf1t, u16* __restrict__ wf2t,
    float* __restrict__ bt) {
  if (blockIdx.x < 12544) {
    const int lane = threadIdx.x & 63;
    const int w = threadIdx.x >> 6;
    const int row = blockIdx.x * 4 + w;
    const int win = row / 49, tok = row - win * 49;
    const int bimg = win >> 6, wloc = win & 63, wi = wloc >> 3, wj = wloc & 7;
    const int r = tok / 7, cc = tok - r * 7;
    const int ho = (wi * 7 + r + 3) % 56;
    const int wo = (wj * 7 + cc + 3) % 56;
    const float* src = x + ((size_t)bimg * 3136 + ho * 56 + wo) * 384;
    float v[6]; float s = 0.f, s2 = 0.f;
#pragma unroll
    for (int i = 0; i < 6; ++i) { float t = src[lane + i * 64]; v[i] = t; s += t; s2 += t * t; }
#pragma unroll
    for (int o = 1; o < 64; o <<= 1) { s += __shfl_xor(s, o); s2 += __shfl_xor(s2, o); }
    float mu = s * (1.f / 384.f);
    float rs = rsqrtf(s2 * (1.f / 384.f) - mu * mu + 1e-5f);
    u16* dst = xw + (size_t)row * 384;
#pragma unroll
    for (int i = 0; i < 6; ++i) {
      int c = lane + i * 64;
      dst[c] = bf16bits((v[i] - mu) * rs * g[c] + b[c]);
    }
    return;
  }
  int idx = (blockIdx.x - 12544) * 256 + threadIdx.x;
  if (idx < 442368) {                       // wqt [1152][384], q cols scaled
    int n = idx / 384, k = idx - n * 384;
    float wv = qkv_w[(size_t)k * 1152 + n];
    if (n < 384) wv *= 0.17677669529663687f;
    wqt[idx] = bf16bits(wv);
    return;
  }
  idx -= 442368;
  if (idx < 147456) {                       // wpt [384][384]
    int n = idx / 384, k = idx - n * 384;
    wpt[idx] = bf16bits(proj_w[(size_t)k * 384 + n]);
    return;
  }
  idx -= 147456;
  if (idx < 589824) {                       // wf1t [1536][384]
    int n = idx / 384, k = idx - n * 384;
    wf1t[idx] = bf16bits(fc1_w[(size_t)k * 1536 + n]);
    return;
  }
  idx -= 589824;
  if (idx < 589824) {                       // wf2t [384][1536]
    int n = idx / 1536, k = idx - n * 1536;
    wf2t[idx] = bf16bits(fc2_w[(size_t)k * 384 + n]);
    return;
  }
  idx -= 589824;
  if (idx >= 196608) return;                // bt [4][12][64][64]
  int col = idx & 63, row = (idx >> 6) & 63;
  int rest = idx >> 12;
  int h = rest % 12, cls = rest / 12;
  float v;
  if (row >= 49 || col >= 49) {
    v = -1e30f;
  } else {
    int qr = row / 7, qc = row - qr * 7;
    int kr = col / 7, kc = col - kr * 7;
    v = rpb[((qr - kr + 6) * 13 + (qc - kc + 6)) * 12 + h];
    bool wi7 = (cls & 2) != 0, wj7 = (cls & 1) != 0;
    int idq = (wi7 ? (qr < 4 ? 3 : 6) : 0) + (wj7 ? (qc < 4 ? 1 : 2) : 0);
    int idk = (wi7 ? (kr < 4 ? 3 : 6) : 0) + (wj7 ? (kc < 4 ? 1 : 2) : 0);
    if (idq != idk) v += -100.f;
  }
  bt[idx] = v;
}

// LN2 (f32 input variant, R14 fallback): reads x2 f32 in d_out, writes bf16 h2
__global__ __launch_bounds__(256) void ln2_f32(const float* __restrict__ xin,
                                               const float* __restrict__ g,
                                               const float* __restrict__ b,
                                               u16* __restrict__ h2) {
  const int lane = threadIdx.x & 63;
  const int w = threadIdx.x >> 6;
  const int row = blockIdx.x * 4 + w;
  const float* src = xin + (size_t)row * 384;
  float v[6]; float s = 0.f, s2 = 0.f;
#pragma unroll
  for (int i = 0; i < 6; ++i) { float t = src[lane + i * 64]; v[i] = t; s += t; s2 += t * t; }
#pragma unroll
  for (int o = 1; o < 64; o <<= 1) { s += __shfl_xor(s, o); s2 += __shfl_xor(s2, o); }
  float mu = s * (1.f / 384.f);
  float rsv = rsqrtf(s2 * (1.f / 384.f) - mu * mu + 1e-5f);
  u16* dst = h2 + (size_t)row * 384;
#pragma unroll
  for (int i = 0; i < 6; ++i) {
    int c = lane + i * 64;
    dst[c] = bf16bits((v[i] - mu) * rsv * g[c] + b[c]);
  }
}

// LN2 (bf16 input variant, R12/R17-validated): reads x2b bf16, writes bf16 h2
__global__ __launch_bounds__(256) void ln2_bf16(const u16* __restrict__ x2b,
                                                const float* __restrict__ g,
                                                const float* __restrict__ b,
                                                u16* __restrict__ h2) {
  const int lane = threadIdx.x & 63;
  const int w = threadIdx.x >> 6;
  const int row = blockIdx.x * 4 + w;
  const u16* src = x2b + (size_t)row * 384;
  float v[6]; float s = 0.f, s2 = 0.f;
#pragma unroll
  for (int i = 0; i < 6; ++i) { float t = bf16dec(src[lane + i * 64]); v[i] = t; s += t; s2 += t * t; }
#pragma unroll
  for (int o = 1; o < 64; o <<= 1) { s += __shfl_xor(s, o); s2 += __shfl_xor(s2, o); }
  float mu = s * (1.f / 384.f);
  float rsv = rsqrtf(s2 * (1.f / 384.f) - mu * mu + 1e-5f);
  u16* dst = h2 + (size_t)row * 384;
#pragma unroll
  for (int i = 0; i < 6; ++i) {
    int c = lane + i * 64;
    dst[c] = bf16bits((v[i] - mu) * rsv * g[c] + b[c]);
  }
}

// ---------------------------------------------------------------------------
// QKV GEMM (128w8 core): [50176,384]x[384,1152] + bias -> [50176][1152].
// ---------------------------------------------------------------------------
__global__ __launch_bounds__(512, 4) void qkv_gemm(const u16* __restrict__ A,
                                                   const u16* __restrict__ Bt,
                                                   const float* __restrict__ bias,
                                                   u16* __restrict__ qkvb) {
  __shared__ char smem[65536];
  int mb, nb;
  xcd_tile(blockIdx.x, 3528, 9, mb, nb);
  f32x4 acc[4][2];
  gemm128w8_core(A, Bt, 384, mb, nb, smem, acc);
  const int lane = threadIdx.x & 63, w = threadIdx.x >> 6;
  const int wr = w >> 2, wc = w & 3;
  const int r0 = mb * 128 + wr * 64 + ((lane >> 4) << 2);
  const int c0 = nb * 128 + wc * 32 + (lane & 15);
  const float qs = (nb < 3) ? 0.17677669529663687f : 1.0f;
  float bj[2];
#pragma unroll
  for (int n = 0; n < 2; ++n) bj[n] = bias[c0 + n * 16] * qs;
#pragma unroll
  for (int m = 0; m < 4; ++m)
#pragma unroll
    for (int e = 0; e < 4; ++e) {
      int row = r0 + m * 16 + e;
      u16* dst = qkvb + (size_t)row * 1152 + c0;
#pragma unroll
      for (int n = 0; n < 2; ++n)
        dst[n * 16] = bf16bits(acc[m][n][e] + bj[n]);
    }
}

// ---------------------------------------------------------------------------
// Attention (R3-proven): 128 threads = 2 independent waves, one (win,head) each.
// ---------------------------------------------------------------------------
__global__ __launch_bounds__(128, 3) void attn2(const u16* __restrict__ qkvb,
                                                const float* __restrict__ bt,
                                                u16* __restrict__ ob) {
  __shared__ char smem[26112];
  const int wv = threadIdx.x >> 6, lane = threadIdx.x & 63;
  char* vts = smem + wv * 13056;          // [32 d][136B]
  char* ps  = smem + wv * 13056 + 4352;   // [64 q][136B]
  const int p = blockIdx.x * 2 + wv;
  const int win = p / 12, head = p - win * 12;
  const int wloc = win & 63, wi = wloc >> 3, wj = wloc & 7;
  const int cls = ((wi == 7) ? 2 : 0) + ((wj == 7) ? 1 : 0);

#pragma unroll
  for (int i = 0; i < 17; ++i) ((u32*)vts)[lane + i * 64] = 0;

  const u16* qg = qkvb + (size_t)win * 49 * 1152 + head * 32;
  const u16* kg = qg + 384;
  const u16* vg = qg + 768;
#pragma unroll
  for (int it = 0; it < 4; ++it) {
    int c = lane + it * 64;
    if (c < 196) {
      int tok = c >> 2, d0 = (c & 3) * 8;
      union { uint4 v; u16 h[8]; } u;
      u.v = *(const uint4*)(vg + (size_t)tok * 1152 + d0);
#pragma unroll
      for (int jj = 0; jj < 8; ++jj)
        *(u16*)(vts + (d0 + jj) * 136 + tok * 2) = u.h[jj];
    }
  }

  const int rsel = lane & 15;
  const int ksub = lane >> 4;
  bf16x8 aq[4], bk[4];
#pragma unroll
  for (int t = 0; t < 4; ++t) {
    int row = t * 16 + rsel;
    union { uint4 u; bf16x8 v; } rq, rk;
    if (row < 49) {
      rq.u = *(const uint4*)(qg + (size_t)row * 1152 + ksub * 8);
      rk.u = *(const uint4*)(kg + (size_t)row * 1152 + ksub * 8);
    } else {
      rq.u = uint4{0, 0, 0, 0};
      rk.u = uint4{0, 0, 0, 0};
    }
    aq[t] = rq.v; bk[t] = rk.v;
  }

  f32x4 s[4][4];
#pragma unroll
  for (int i = 0; i < 4; ++i)
#pragma unroll
    for (int j = 0; j < 4; ++j) s[i][j] = f32x4{0.f, 0.f, 0.f, 0.f};
#pragma unroll
  for (int i = 0; i < 4; ++i)
#pragma unroll
    for (int j = 0; j < 4; ++j)
      s[i][j] = __builtin_amdgcn_mfma_f32_16x16x32_bf16(aq[i], bk[j], s[i][j], 0, 0, 0);

  const float* tb = bt + ((size_t)(cls * 12 + head) << 12);
  const int rowsub = ksub << 2;
#pragma unroll
  for (int i = 0; i < 4; ++i) {
    float bl[4][4];
#pragma unroll
    for (int e = 0; e < 4; ++e) {
      int row = i * 16 + rowsub + e;
#pragma unroll
      for (int j = 0; j < 4; ++j) bl[e][j] = tb[row * 64 + j * 16 + rsel];
    }
#pragma unroll
    for (int e = 0; e < 4; ++e) {
      int row = i * 16 + rowsub + e;
      float v[4];
#pragma unroll
      for (int j = 0; j < 4; ++j) v[j] = s[i][j][e] + bl[e][j];
      float m = fmaxf(fmaxf(v[0], v[1]), fmaxf(v[2], v[3]));
#pragma unroll
      for (int o = 1; o < 16; o <<= 1) m = fmaxf(m, __shfl_xor(m, o));
      float pr[4]; float sum = 0.f;
#pragma unroll
      for (int j = 0; j < 4; ++j) { pr[j] = __expf(v[j] - m); sum += pr[j]; }
#pragma unroll
      for (int o = 1; o < 16; o <<= 1) sum += __shfl_xor(sum, o);
      float inv = 1.f / sum;
#pragma unroll
      for (int j = 0; j < 4; ++j)
        *(u16*)(ps + row * 136 + (j * 16 + rsel) * 2) = bf16bits(pr[j] * inv);
    }
  }

  f32x4 o[4][2];
#pragma unroll
  for (int i = 0; i < 4; ++i)
#pragma unroll
    for (int j = 0; j < 2; ++j) o[i][j] = f32x4{0.f, 0.f, 0.f, 0.f};
#pragma unroll
  for (int kk = 0; kk < 2; ++kk) {
    bf16x8 ap[4], bv[2];
#pragma unroll
    for (int t = 0; t < 4; ++t)
      ap[t] = *(const bf16x8*)(ps + (t * 16 + rsel) * 136 + kk * 64 + ksub * 16);
#pragma unroll
    for (int t = 0; t < 2; ++t)
      bv[t] = *(const bf16x8*)(vts + (t * 16 + rsel) * 136 + kk * 64 + ksub * 16);
#pragma unroll
    for (int i = 0; i < 4; ++i)
#pragma unroll
      for (int j = 0; j < 2; ++j)
        o[i][j] = __builtin_amdgcn_mfma_f32_16x16x32_bf16(ap[i], bv[j], o[i][j], 0, 0, 0);
  }

  u16* obase = ob + (size_t)win * 49 * 384 + head * 32;
#pragma unroll
  for (int i = 0; i < 4; ++i)
#pragma unroll
    for (int j = 0; j < 2; ++j)
#pragma unroll
      for (int e = 0; e < 4; ++e) {
        int tok = i * 16 + rowsub + e;
        if (tok < 49)
          obase[(size_t)tok * 384 + j * 16 + rsel] = bf16bits(o[i][j][e]);
      }
}

// ---------------------------------------------------------------------------
// proj GEMM, f32-residual variant (R14 fallback).
// ---------------------------------------------------------------------------
__global__ __launch_bounds__(512, 4) void proj_f32(const u16* __restrict__ A,
                                                   const u16* __restrict__ Bt,
                                                   const float* __restrict__ bias,
                                                   const float* __restrict__ xres,
                                                   float* __restrict__ out) {
  __shared__ char smem[65536];
  int mb, nb;
  xcd_tile(blockIdx.x, 1176, 3, mb, nb);
  f32x4 acc[4][2];
  gemm128w8_core(A, Bt, 384, mb, nb, smem, acc);
  const int lane = threadIdx.x & 63, w = threadIdx.x >> 6;
  const int wr = w >> 2, wc = w & 3;
  const int r0 = mb * 128 + wr * 64 + ((lane >> 4) << 2);
  const int c0 = nb * 128 + wc * 32 + (lane & 15);
  float bj[2];
#pragma unroll
  for (int n = 0; n < 2; ++n) bj[n] = bias[c0 + n * 16];
#pragma unroll
  for (int m = 0; m < 4; ++m)
#pragma unroll
    for (int e = 0; e < 4; ++e) {
      int row = r0 + m * 16 + e;
      int wn = row / 49, tok = row - wn * 49;
      int bimg = wn >> 6, wloc = wn & 63, wi = wloc >> 3, wj = wloc & 7;
      int r = tok / 7, cc = tok - r * 7;
      int t1 = wi * 7 + r + 3;  int ho = t1 >= 56 ? t1 - 56 : t1;
      int t2 = wj * 7 + cc + 3; int wo = t2 >= 56 ? t2 - 56 : t2;
      size_t gbase = ((size_t)bimg * 3136 + ho * 56 + wo) * 384 + c0;
#pragma unroll
      for (int n = 0; n < 2; ++n) {
        size_t gi = gbase + n * 16;
        out[gi] = acc[m][n][e] + bj[n] + xres[gi];
      }
    }
}

// proj GEMM, bf16-residual variant (R12/R17-validated): -> x2b bf16.
__global__ __launch_bounds__(512, 4) void proj_bf16(const u16* __restrict__ A,
                                                    const u16* __restrict__ Bt,
                                                    const float* __restrict__ bias,
                                                    const float* __restrict__ xres,
                                                    u16* __restrict__ x2b) {
  __shared__ char smem[65536];
  int mb, nb;
  xcd_tile(blockIdx.x, 1176, 3, mb, nb);
  f32x4 acc[4][2];
  gemm128w8_core(A, Bt, 384, mb, nb, smem, acc);
  const int lane = threadIdx.x & 63, w = threadIdx.x >> 6;
  const int wr = w >> 2, wc = w & 3;
  const int r0 = mb * 128 + wr * 64 + ((lane >> 4) << 2);
  const int c0 = nb * 128 + wc * 32 + (lane & 15);
  float bj[2];
#pragma unroll
  for (int n = 0; n < 2; ++n) bj[n] = bias[c0 + n * 16];
#pragma unroll
  for (int m = 0; m < 4; ++m)
#pragma unroll
    for (int e = 0; e < 4; ++e) {
      int row = r0 + m * 16 + e;
      int wn = row / 49, tok = row - wn * 49;
      int bimg = wn >> 6, wloc = wn & 63, wi = wloc >> 3, wj = wloc & 7;
      int r = tok / 7, cc = tok - r * 7;
      int t1 = wi * 7 + r + 3;  int ho = t1 >= 56 ? t1 - 56 : t1;
      int t2 = wj * 7 + cc + 3; int wo = t2 >= 56 ? t2 - 56 : t2;
      size_t gbase = ((size_t)bimg * 3136 + ho * 56 + wo) * 384 + c0;
#pragma unroll
      for (int n = 0; n < 2; ++n) {
        size_t gi = gbase + n * 16;
        x2b[gi] = bf16bits(acc[m][n][e] + bj[n] + xres[gi]);
      }
    }
}

// fc1 (128w8 core): [50176,384]x[384,1536] + bias + exact erf GELU -> bf16
__global__ __launch_bounds__(512, 4) void fc1_gemm(const u16* __restrict__ A,
                                                   const u16* __restrict__ Bt,
                                                   const float* __restrict__ bias,
                                                   u16* __restrict__ h3) {
  __shared__ char smem[65536];
  int mb, nb;
  xcd_tile(blockIdx.x, 4704, 12, mb, nb);
  f32x4 acc[4][2];
  gemm128w8_core(A, Bt, 384, mb, nb, smem, acc);
  const int lane = threadIdx.x & 63, w = threadIdx.x >> 6;
  const int wr = w >> 2, wc = w & 3;
  const int r0 = mb * 128 + wr * 64 + ((lane >> 4) << 2);
  const int c0 = nb * 128 + wc * 32 + (lane & 15);
  float bj[2];
#pragma unroll
  for (int n = 0; n < 2; ++n) bj[n] = bias[c0 + n * 16];
#pragma unroll
  for (int m = 0; m < 4; ++m)
#pragma unroll
    for (int e = 0; e < 4; ++e) {
      int row = r0 + m * 16 + e;
      u16* dst = h3 + (size_t)row * 1536 + c0;
#pragma unroll
      for (int n = 0; n < 2; ++n) {
        float v = acc[m][n][e] + bj[n];
        float gl = 0.5f * v * (1.f + erff(v * 0.70710678118654752f));
        dst[n * 16] = bf16bits(gl);
      }
    }
}

// fc2 RMW variant (fallback): out += mlp (out pre-holds x2 f32).
__global__ __launch_bounds__(512, 4) void fc2_rmw(const u16* __restrict__ A,
                                                  const u16* __restrict__ Bt,
                                                  const float* __restrict__ bias,
                                                  float* __restrict__ out) {
  __shared__ char smem[65536];
  int mb, nb;
  xcd_tile(blockIdx.x, 1176, 3, mb, nb);
  f32x4 acc[4][2];
  gemm128w8_core(A, Bt, 1536, mb, nb, smem, acc);
  const int lane = threadIdx.x & 63, w = threadIdx.x >> 6;
  const int wr = w >> 2, wc = w & 3;
  const int r0 = mb * 128 + wr * 64 + ((lane >> 4) << 2);
  const int c0 = nb * 128 + wc * 32 + (lane & 15);
  float bj[2];
#pragma unroll
  for (int n = 0; n < 2; ++n) bj[n] = bias[c0 + n * 16];
#pragma unroll
  for (int m = 0; m < 4; ++m)
#pragma unroll
    for (int e = 0; e < 4; ++e) {
      int row = r0 + m * 16 + e;
      float* dst = out + (size_t)row * 384 + c0;
#pragma unroll
      for (int n = 0; n < 2; ++n)
        dst[n * 16] += acc[m][n][e] + bj[n];
    }
}

// fc2 write-once variant (fast): out = bf16dec(x2b) + mlp.
__global__ __launch_bounds__(512, 4) void fc2_once(const u16* __restrict__ A,
                                                   const u16* __restrict__ Bt,
                                                   const float* __restrict__ bias,
                                                   const u16* __restrict__ x2b,
                                                   float* __restrict__ out) {
  __shared__ char smem[65536];
  int mb, nb;
  xcd_tile(blockIdx.x, 1176, 3, mb, nb);
  f32x4 acc[4][2];
  gemm128w8_core(A, Bt, 1536, mb, nb, smem, acc);
  const int lane = threadIdx.x & 63, w = threadIdx.x >> 6;
  const int wr = w >> 2, wc = w & 3;
  const int r0 = mb * 128 + wr * 64 + ((lane >> 4) << 2);
  const int c0 = nb * 128 + wc * 32 + (lane & 15);
  float bj[2];
#pragma unroll
  for (int n = 0; n < 2; ++n) bj[n] = bias[c0 + n * 16];
#pragma unroll
  for (int m = 0; m < 4; ++m)
#pragma unroll
    for (int e = 0; e < 4; ++e) {
      size_t row = (size_t)(r0 + m * 16 + e);
#pragma unroll
      for (int n = 0; n < 2; ++n) {
        size_t gi = row * 384 + c0 + n * 16;
        out[gi] = bf16dec(x2b[gi]) + acc[m][n][e] + bj[n];
      }
    }
}

// ---------------------------------------------------------------------------
extern "C" void kernel_launch(void* const* d_in, const int* in_sizes, int n_in,
                              void* d_out, int out_size, void* d_ws, size_t ws_size,
                              hipStream_t stream) {
  const float* x      = (const float*)d_in[0];
  const float* n1g    = (const float*)d_in[1];
  const float* n1b    = (const float*)d_in[2];
  const float* qkv_w  = (const float*)d_in[3];
  const float* qkv_b  = (const float*)d_in[4];
  const float* rpb    = (const float*)d_in[5];
  const float* proj_w = (const float*)d_in[6];
  const float* proj_b = (const float*)d_in[7];
  const float* n2g    = (const float*)d_in[8];
  const float* n2b    = (const float*)d_in[9];
  const float* fc1_w  = (const float*)d_in[10];
  const float* fc1_b  = (const float*)d_in[11];
  const float* fc2_w  = (const float*)d_in[12];
  const float* fc2_b  = (const float*)d_in[13];
  float* out = (float*)d_out;

  char* ws = (char*)d_ws;
  const size_t S = (size_t)50176 * 384 * 2;   // 38.5 MB
  const size_t WB = (size_t)(442368 + 147456 + 589824 + 589824) * 2; // weights bytes
  const bool fast = ws_size >= 7 * S + WB + 786432 + (size_t)8 * 1024 * 1024;

  u16* xw = (u16*)ws;                         // [0,S): LN1 out / attn out

  if (fast) {
    // FAST layout (bf16 residual, unchunked):
    // qkvb [S,4S); post-attn: x2b [S,2S), h2 [2S,3S); h3 [3S,7S);
    // bt [7S, +768K); weights after.
    u16* qkvb = (u16*)(ws + S);
    u16* x2b  = (u16*)(ws + S);
    u16* h2   = (u16*)(ws + 2 * S);
    u16* h3   = (u16*)(ws + 3 * S);
    float* bias_t = (float*)(ws + 7 * S);
    u16* wqt  = (u16*)(ws + 7 * S + 786432);
    u16* wpt  = wqt  + 1152 * 384;
    u16* wf1t = wpt  + 384 * 384;
    u16* wf2t = wf1t + 1536 * 384;

    ln1_prep<<<20224, 256, 0, stream>>>(x, n1g, n1b, xw,
                                        qkv_w, proj_w, fc1_w, fc2_w, rpb,
                                        wqt, wpt, wf1t, wf2t, bias_t);
    qkv_gemm<<<3528, 512, 0, stream>>>(xw, wqt, qkv_b, qkvb);
    attn2<<<6144, 128, 0, stream>>>(qkvb, bias_t, xw);
    proj_bf16<<<1176, 512, 0, stream>>>(xw, wpt, proj_b, x, x2b);
    ln2_bf16<<<12544, 256, 0, stream>>>(x2b, n2g, n2b, h2);
    fc1_gemm<<<4704, 512, 0, stream>>>(h2, wf1t, fc1_b, h3);
    fc2_once<<<1176, 512, 0, stream>>>(h3, wf2t, fc2_b, x2b, out);
  } else {
    // FALLBACK = R14 layout (f32 residual in d_out):
    u16* qkvb = (u16*)(ws + S);
    u16* h2   = (u16*)(ws + 4 * S);
    u16* h3   = (u16*)ws;                     // aliases xw+qkvb (dead)
    float* bias_t = (float*)(ws + 4 * S);     // aliases h2 (free until ln2)
    u16* wqt  = (u16*)(ws + 5 * S);
    u16* wpt  = wqt  + 1152 * 384;
    u16* wf1t = wpt  + 384 * 384;
    u16* wf2t = wf1t + 1536 * 384;

    ln1_prep<<<20224, 256, 0, stream>>>(x, n1g, n1b, xw,
                                        qkv_w, proj_w, fc1_w, fc2_w, rpb,
                                        wqt, wpt, wf1t, wf2t, bias_t);
    qkv_gemm<<<3528, 512, 0, stream>>>(xw, wqt, qkv_b, qkvb);
    attn2<<<6144, 128, 0, stream>>>(qkvb, bias_t, xw);
    proj_f32<<<1176, 512, 0, stream>>>(xw, wpt, proj_b, x, out);
    ln2_f32<<<12544, 256, 0, stream>>>(out, n2g, n2b, h2);
    fc1_gemm<<<4704, 512, 0, stream>>>(h2, wf1t, fc1_b, h3);
    fc2_rmw<<<1176, 512, 0, stream>>>(h3, wf2t, fc2_b, out);
  }
}

// Round 20
// 377.831 us; speedup vs baseline: 1.0660x; 1.0114x over previous
//
#include <hip/hip_runtime.h>
#include <cstdint>
#include <cstddef>

using u16 = unsigned short;
using u32 = unsigned int;

typedef __bf16 bf16x8 __attribute__((ext_vector_type(8)));
typedef float f32x4 __attribute__((ext_vector_type(4)));

#define AS1 __attribute__((address_space(1)))
#define AS3 __attribute__((address_space(3)))

__device__ __forceinline__ void gload16(const void* g, void* l) {
  __builtin_amdgcn_global_load_lds((const AS1 u32*)g, (AS3 u32*)l, 16, 0, 0);
}

__device__ __forceinline__ u16 bf16bits(float f) {
  u32 u = __float_as_uint(f);
  u32 r = (u + 0x7fffu + ((u >> 16) & 1u)) >> 16;
  return (u16)r;
}

__device__ __forceinline__ float bf16dec(u16 v) {
  return __uint_as_float(((u32)v) << 16);
}

// XCD-chunked bijective block remap (m204), nb-fast so consecutive blocks on
// one XCD share the A-panel (L2-resident).
__device__ __forceinline__ void xcd_tile(int bid, int nwg, int nfast,
                                         int& mb, int& nb) {
  int q = nwg >> 3, r = nwg & 7;
  int xcd = bid & 7, idx = bid >> 3;
  int nid = (xcd < r ? xcd * (q + 1) : r * (q + 1) + (xcd - r) * q) + idx;
  nb = nid % nfast;
  mb = nid / nfast;
}

// ---------------------------------------------------------------------------
// 128x128 bf16 pipelined GEMM core, 8-wave (R10/R13/R14-proven, best measured):
// BK=64, 2 buffers (64KB LDS -> 2 blocks/CU), counted vmcnt, 512 thr =
// 8 waves (2M x 4N), per-wave C = 64x32 (4x2 frags).  16 waves/CU.
// Per iter t: STAGE(t+1 -> buf[(t+1)&1], 4 gloads/thr) -> vmcnt(4) [tile t
// complete, t+1 in flight] -> s_barrier -> ds_read buf[t&1] + 16 MFMA/wave
// -> lgkm(0) -> s_barrier.  Distance-1 prefetch race-free (R9/R10-verified).
// ---------------------------------------------------------------------------
__device__ __forceinline__ void gemm128w8_core(const u16* __restrict__ A,
                                               const u16* __restrict__ Bt,
                                               int K, int mb, int nb,
                                               char* smem, f32x4 (&acc)[4][2]) {
  const int tid = (int)threadIdx.x;
  const int lane = tid & 63;
  const int w = tid >> 6;
  const int wr = w >> 2, wc = w & 3;

  const int srow = w * 16 + (lane >> 3);       // round r adds 8
  const int schk = lane & 7;
  const int gswz = schk ^ (srow & 7);          // same for both rounds (row+8)
  const u16* gA0 = A  + (size_t)(mb * 128 + srow) * K + gswz * 8;
  const u16* gA1 = A  + (size_t)(mb * 128 + srow + 8) * K + gswz * 8;
  const u16* gB0 = Bt + (size_t)(nb * 128 + srow) * K + gswz * 8;
  const u16* gB1 = Bt + (size_t)(nb * 128 + srow + 8) * K + gswz * 8;
  const int lwa = w * 2048;                    // wave-uniform LDS slab base

#pragma unroll
  for (int i = 0; i < 4; ++i)
#pragma unroll
    for (int j = 0; j < 2; ++j)
      acc[i][j] = f32x4{0.f, 0.f, 0.f, 0.f};

  const int rsel = lane & 15;
  const int csel = lane >> 4;
  const int sx = rsel & 7;
  int aoff[2][4], boff[2][2];
#pragma unroll
  for (int kk = 0; kk < 2; ++kk) {
#pragma unroll
    for (int m = 0; m < 4; ++m) {
      int ra = wr * 64 + m * 16 + rsel;
      aoff[kk][m] = ra * 128 + (((kk * 4 + csel) ^ sx) << 4);
    }
#pragma unroll
    for (int n = 0; n < 2; ++n) {
      int rb = wc * 32 + n * 16 + rsel;
      boff[kk][n] = rb * 128 + (((kk * 4 + csel) ^ sx) << 4);
    }
  }

  const int nk = K >> 6;

#define STAGE_W8(kt, b)                                                        \
  {                                                                            \
    char* As_ = smem + (b) * 32768;                                            \
    char* Bs_ = As_ + 16384;                                                   \
    gload16(gA0 + (size_t)(kt) * 64, As_ + lwa);                               \
    gload16(gA1 + (size_t)(kt) * 64, As_ + lwa + 1024);                        \
    gload16(gB0 + (size_t)(kt) * 64, Bs_ + lwa);                               \
    gload16(gB1 + (size_t)(kt) * 64, Bs_ + lwa + 1024);                        \
  }

  STAGE_W8(0, 0);

  for (int kt = 0; kt < nk; ++kt) {
    if (kt + 1 < nk) {
      STAGE_W8(kt + 1, (kt + 1) & 1);
      asm volatile("s_waitcnt vmcnt(4)" ::: "memory");
    } else {
      asm volatile("s_waitcnt vmcnt(0)" ::: "memory");
    }
    __builtin_amdgcn_s_barrier();

    char* As = smem + (kt & 1) * 32768;
    char* Bs = As + 16384;
#pragma unroll
    for (int kk = 0; kk < 2; ++kk) {
      bf16x8 af[4], bf[2];
#pragma unroll
      for (int m = 0; m < 4; ++m) af[m] = *(const bf16x8*)(As + aoff[kk][m]);
#pragma unroll
      for (int n = 0; n < 2; ++n) bf[n] = *(const bf16x8*)(Bs + boff[kk][n]);
      __builtin_amdgcn_s_setprio(1);
#pragma unroll
      for (int m = 0; m < 4; ++m)
#pragma unroll
        for (int n = 0; n < 2; ++n)
          acc[m][n] = __builtin_amdgcn_mfma_f32_16x16x32_bf16(af[m], bf[n], acc[m][n], 0, 0, 0);
      __builtin_amdgcn_s_setprio(0);
    }
    asm volatile("s_waitcnt lgkmcnt(0)" ::: "memory");
    __builtin_amdgcn_s_barrier();
  }
#undef STAGE_W8
}

// ---------------------------------------------------------------------------
// ln1_prep: fused LN1(+roll+window gather) AND weight transposes + bias table.
// Blocks [0,12544): ln1 rows.  Blocks [12544,20224): prep.
// q-scale 1/sqrt(32) folded into wqt columns < 384.
// ---------------------------------------------------------------------------
__global__ __launch_bounds__(256) void ln1_prep(
    const float* __restrict__ x, const float* __restrict__ g,
    const float* __restrict__ b, u16* __restrict__ xw,
    const float* __restrict__ qkv_w, const float* __restrict__ proj_w,
    const float* __restrict__ fc1_w, const float* __restrict__ fc2_w,
    const float* __restrict__ rpb,
    u16* __restrict__ wqt, u16* __restrict__ wpt,
    u16* __restrict__ wf1t, u16* __restrict__ wf2t,
    float* __restrict__ bt) {
  if (blockIdx.x < 12544) {
    const int lane = threadIdx.x & 63;
    const int w = threadIdx.x >> 6;
    const int row = blockIdx.x * 4 + w;
    const int win = row / 49, tok = row - win * 49;
    const int bimg = win >> 6, wloc = win & 63, wi = wloc >> 3, wj = wloc & 7;
    const int r = tok / 7, cc = tok - r * 7;
    const int ho = (wi * 7 + r + 3) % 56;
    const int wo = (wj * 7 + cc + 3) % 56;
    const float* src = x + ((size_t)bimg * 3136 + ho * 56 + wo) * 384;
    float v[6]; float s = 0.f, s2 = 0.f;
#pragma unroll
    for (int i = 0; i < 6; ++i) { float t = src[lane + i * 64]; v[i] = t; s += t; s2 += t * t; }
#pragma unroll
    for (int o = 1; o < 64; o <<= 1) { s += __shfl_xor(s, o); s2 += __shfl_xor(s2, o); }
    float mu = s * (1.f / 384.f);
    float rs = rsqrtf(s2 * (1.f / 384.f) - mu * mu + 1e-5f);
    u16* dst = xw + (size_t)row * 384;
#pragma unroll
    for (int i = 0; i < 6; ++i) {
      int c = lane + i * 64;
      dst[c] = bf16bits((v[i] - mu) * rs * g[c] + b[c]);
    }
    return;
  }
  int idx = (blockIdx.x - 12544) * 256 + threadIdx.x;
  if (idx < 442368) {                       // wqt [1152][384], q cols scaled
    int n = idx / 384, k = idx - n * 384;
    float wv = qkv_w[(size_t)k * 1152 + n];
    if (n < 384) wv *= 0.17677669529663687f;
    wqt[idx] = bf16bits(wv);
    return;
  }
  idx -= 442368;
  if (idx < 147456) {                       // wpt [384][384]
    int n = idx / 384, k = idx - n * 384;
    wpt[idx] = bf16bits(proj_w[(size_t)k * 384 + n]);
    return;
  }
  idx -= 147456;
  if (idx < 589824) {                       // wf1t [1536][384]
    int n = idx / 384, k = idx - n * 384;
    wf1t[idx] = bf16bits(fc1_w[(size_t)k * 1536 + n]);
    return;
  }
  idx -= 589824;
  if (idx < 589824) {                       // wf2t [384][1536]
    int n = idx / 1536, k = idx - n * 1536;
    wf2t[idx] = bf16bits(fc2_w[(size_t)k * 384 + n]);
    return;
  }
  idx -= 589824;
  if (idx >= 196608) return;                // bt [4][12][64][64]
  int col = idx & 63, row = (idx >> 6) & 63;
  int rest = idx >> 12;
  int h = rest % 12, cls = rest / 12;
  float v;
  if (row >= 49 || col >= 49) {
    v = -1e30f;
  } else {
    int qr = row / 7, qc = row - qr * 7;
    int kr = col / 7, kc = col - kr * 7;
    v = rpb[((qr - kr + 6) * 13 + (qc - kc + 6)) * 12 + h];
    bool wi7 = (cls & 2) != 0, wj7 = (cls & 1) != 0;
    int idq = (wi7 ? (qr < 4 ? 3 : 6) : 0) + (wj7 ? (qc < 4 ? 1 : 2) : 0);
    int idk = (wi7 ? (kr < 4 ? 3 : 6) : 0) + (wj7 ? (kc < 4 ? 1 : 2) : 0);
    if (idq != idk) v += -100.f;
  }
  bt[idx] = v;
}

// LN2 (f32 input variant, R14 fallback): reads x2 f32 in d_out, writes bf16 h2
__global__ __launch_bounds__(256) void ln2_f32(const float* __restrict__ xin,
                                               const float* __restrict__ g,
                                               const float* __restrict__ b,
                                               u16* __restrict__ h2) {
  const int lane = threadIdx.x & 63;
  const int w = threadIdx.x >> 6;
  const int row = blockIdx.x * 4 + w;
  const float* src = xin + (size_t)row * 384;
  float v[6]; float s = 0.f, s2 = 0.f;
#pragma unroll
  for (int i = 0; i < 6; ++i) { float t = src[lane + i * 64]; v[i] = t; s += t; s2 += t * t; }
#pragma unroll
  for (int o = 1; o < 64; o <<= 1) { s += __shfl_xor(s, o); s2 += __shfl_xor(s2, o); }
  float mu = s * (1.f / 384.f);
  float rsv = rsqrtf(s2 * (1.f / 384.f) - mu * mu + 1e-5f);
  u16* dst = h2 + (size_t)row * 384;
#pragma unroll
  for (int i = 0; i < 6; ++i) {
    int c = lane + i * 64;
    dst[c] = bf16bits((v[i] - mu) * rsv * g[c] + b[c]);
  }
}

// LN2 (bf16 input variant, R12/R17-validated): reads x2b bf16, writes bf16 h2
__global__ __launch_bounds__(256) void ln2_bf16(const u16* __restrict__ x2b,
                                                const float* __restrict__ g,
                                                const float* __restrict__ b,
                                                u16* __restrict__ h2) {
  const int lane = threadIdx.x & 63;
  const int w = threadIdx.x >> 6;
  const int row = blockIdx.x * 4 + w;
  const u16* src = x2b + (size_t)row * 384;
  float v[6]; float s = 0.f, s2 = 0.f;
#pragma unroll
  for (int i = 0; i < 6; ++i) { float t = bf16dec(src[lane + i * 64]); v[i] = t; s += t; s2 += t * t; }
#pragma unroll
  for (int o = 1; o < 64; o <<= 1) { s += __shfl_xor(s, o); s2 += __shfl_xor(s2, o); }
  float mu = s * (1.f / 384.f);
  float rsv = rsqrtf(s2 * (1.f / 384.f) - mu * mu + 1e-5f);
  u16* dst = h2 + (size_t)row * 384;
#pragma unroll
  for (int i = 0; i < 6; ++i) {
    int c = lane + i * 64;
    dst[c] = bf16bits((v[i] - mu) * rsv * g[c] + b[c]);
  }
}

// ---------------------------------------------------------------------------
// QKV GEMM (128w8 core): [50176,384]x[384,1152] + bias -> [50176][1152].
// ---------------------------------------------------------------------------
__global__ __launch_bounds__(512, 4) void qkv_gemm(const u16* __restrict__ A,
                                                   const u16* __restrict__ Bt,
                                                   const float* __restrict__ bias,
                                                   u16* __restrict__ qkvb) {
  __shared__ char smem[65536];
  int mb, nb;
  xcd_tile(blockIdx.x, 3528, 9, mb, nb);
  f32x4 acc[4][2];
  gemm128w8_core(A, Bt, 384, mb, nb, smem, acc);
  const int lane = threadIdx.x & 63, w = threadIdx.x >> 6;
  const int wr = w >> 2, wc = w & 3;
  const int r0 = mb * 128 + wr * 64 + ((lane >> 4) << 2);
  const int c0 = nb * 128 + wc * 32 + (lane & 15);
  const float qs = (nb < 3) ? 0.17677669529663687f : 1.0f;
  float bj[2];
#pragma unroll
  for (int n = 0; n < 2; ++n) bj[n] = bias[c0 + n * 16] * qs;
#pragma unroll
  for (int m = 0; m < 4; ++m)
#pragma unroll
    for (int e = 0; e < 4; ++e) {
      int row = r0 + m * 16 + e;
      u16* dst = qkvb + (size_t)row * 1152 + c0;
#pragma unroll
      for (int n = 0; n < 2; ++n)
        dst[n * 16] = bf16bits(acc[m][n][e] + bj[n]);
    }
}

// ---------------------------------------------------------------------------
// Attention (R3-proven): 128 threads = 2 independent waves, one (win,head) each.
// ---------------------------------------------------------------------------
__global__ __launch_bounds__(128, 3) void attn2(const u16* __restrict__ qkvb,
                                                const float* __restrict__ bt,
                                                u16* __restrict__ ob) {
  __shared__ char smem[26112];
  const int wv = threadIdx.x >> 6, lane = threadIdx.x & 63;
  char* vts = smem + wv * 13056;          // [32 d][136B]
  char* ps  = smem + wv * 13056 + 4352;   // [64 q][136B]
  const int p = blockIdx.x * 2 + wv;
  const int win = p / 12, head = p - win * 12;
  const int wloc = win & 63, wi = wloc >> 3, wj = wloc & 7;
  const int cls = ((wi == 7) ? 2 : 0) + ((wj == 7) ? 1 : 0);

#pragma unroll
  for (int i = 0; i < 17; ++i) ((u32*)vts)[lane + i * 64] = 0;

  const u16* qg = qkvb + (size_t)win * 49 * 1152 + head * 32;
  const u16* kg = qg + 384;
  const u16* vg = qg + 768;
#pragma unroll
  for (int it = 0; it < 4; ++it) {
    int c = lane + it * 64;
    if (c < 196) {
      int tok = c >> 2, d0 = (c & 3) * 8;
      union { uint4 v; u16 h[8]; } u;
      u.v = *(const uint4*)(vg + (size_t)tok * 1152 + d0);
#pragma unroll
      for (int jj = 0; jj < 8; ++jj)
        *(u16*)(vts + (d0 + jj) * 136 + tok * 2) = u.h[jj];
    }
  }

  const int rsel = lane & 15;
  const int ksub = lane >> 4;
  bf16x8 aq[4], bk[4];
#pragma unroll
  for (int t = 0; t < 4; ++t) {
    int row = t * 16 + rsel;
    union { uint4 u; bf16x8 v; } rq, rk;
    if (row < 49) {
      rq.u = *(const uint4*)(qg + (size_t)row * 1152 + ksub * 8);
      rk.u = *(const uint4*)(kg + (size_t)row * 1152 + ksub * 8);
    } else {
      rq.u = uint4{0, 0, 0, 0};
      rk.u = uint4{0, 0, 0, 0};
    }
    aq[t] = rq.v; bk[t] = rk.v;
  }

  f32x4 s[4][4];
#pragma unroll
  for (int i = 0; i < 4; ++i)
#pragma unroll
    for (int j = 0; j < 4; ++j) s[i][j] = f32x4{0.f, 0.f, 0.f, 0.f};
#pragma unroll
  for (int i = 0; i < 4; ++i)
#pragma unroll
    for (int j = 0; j < 4; ++j)
      s[i][j] = __builtin_amdgcn_mfma_f32_16x16x32_bf16(aq[i], bk[j], s[i][j], 0, 0, 0);

  const float* tb = bt + ((size_t)(cls * 12 + head) << 12);
  const int rowsub = ksub << 2;
#pragma unroll
  for (int i = 0; i < 4; ++i) {
    float bl[4][4];
#pragma unroll
    for (int e = 0; e < 4; ++e) {
      int row = i * 16 + rowsub + e;
#pragma unroll
      for (int j = 0; j < 4; ++j) bl[e][j] = tb[row * 64 + j * 16 + rsel];
    }
#pragma unroll
    for (int e = 0; e < 4; ++e) {
      int row = i * 16 + rowsub + e;
      float v[4];
#pragma unroll
      for (int j = 0; j < 4; ++j) v[j] = s[i][j][e] + bl[e][j];
      float m = fmaxf(fmaxf(v[0], v[1]), fmaxf(v[2], v[3]));
#pragma unroll
      for (int o = 1; o < 16; o <<= 1) m = fmaxf(m, __shfl_xor(m, o));
      float pr[4]; float sum = 0.f;
#pragma unroll
      for (int j = 0; j < 4; ++j) { pr[j] = __expf(v[j] - m); sum += pr[j]; }
#pragma unroll
      for (int o = 1; o < 16; o <<= 1) sum += __shfl_xor(sum, o);
      float inv = 1.f / sum;
#pragma unroll
      for (int j = 0; j < 4; ++j)
        *(u16*)(ps + row * 136 + (j * 16 + rsel) * 2) = bf16bits(pr[j] * inv);
    }
  }

  f32x4 o[4][2];
#pragma unroll
  for (int i = 0; i < 4; ++i)
#pragma unroll
    for (int j = 0; j < 2; ++j) o[i][j] = f32x4{0.f, 0.f, 0.f, 0.f};
#pragma unroll
  for (int kk = 0; kk < 2; ++kk) {
    bf16x8 ap[4], bv[2];
#pragma unroll
    for (int t = 0; t < 4; ++t)
      ap[t] = *(const bf16x8*)(ps + (t * 16 + rsel) * 136 + kk * 64 + ksub * 16);
#pragma unroll
    for (int t = 0; t < 2; ++t)
      bv[t] = *(const bf16x8*)(vts + (t * 16 + rsel) * 136 + kk * 64 + ksub * 16);
#pragma unroll
    for (int i = 0; i < 4; ++i)
#pragma unroll
      for (int j = 0; j < 2; ++j)
        o[i][j] = __builtin_amdgcn_mfma_f32_16x16x32_bf16(ap[i], bv[j], o[i][j], 0, 0, 0);
  }

  u16* obase = ob + (size_t)win * 49 * 384 + head * 32;
#pragma unroll
  for (int i = 0; i < 4; ++i)
#pragma unroll
    for (int j = 0; j < 2; ++j)
#pragma unroll
      for (int e = 0; e < 4; ++e) {
        int tok = i * 16 + rowsub + e;
        if (tok < 49)
          obase[(size_t)tok * 384 + j * 16 + rsel] = bf16bits(o[i][j][e]);
      }
}

// ---------------------------------------------------------------------------
// proj GEMM, f32-residual variant (R14 fallback).
// ---------------------------------------------------------------------------
__global__ __launch_bounds__(512, 4) void proj_f32(const u16* __restrict__ A,
                                                   const u16* __restrict__ Bt,
                                                   const float* __restrict__ bias,
                                                   const float* __restrict__ xres,
                                                   float* __restrict__ out) {
  __shared__ char smem[65536];
  int mb, nb;
  xcd_tile(blockIdx.x, 1176, 3, mb, nb);
  f32x4 acc[4][2];
  gemm128w8_core(A, Bt, 384, mb, nb, smem, acc);
  const int lane = threadIdx.x & 63, w = threadIdx.x >> 6;
  const int wr = w >> 2, wc = w & 3;
  const int r0 = mb * 128 + wr * 64 + ((lane >> 4) << 2);
  const int c0 = nb * 128 + wc * 32 + (lane & 15);
  float bj[2];
#pragma unroll
  for (int n = 0; n < 2; ++n) bj[n] = bias[c0 + n * 16];
#pragma unroll
  for (int m = 0; m < 4; ++m)
#pragma unroll
    for (int e = 0; e < 4; ++e) {
      int row = r0 + m * 16 + e;
      int wn = row / 49, tok = row - wn * 49;
      int bimg = wn >> 6, wloc = wn & 63, wi = wloc >> 3, wj = wloc & 7;
      int r = tok / 7, cc = tok - r * 7;
      int t1 = wi * 7 + r + 3;  int ho = t1 >= 56 ? t1 - 56 : t1;
      int t2 = wj * 7 + cc + 3; int wo = t2 >= 56 ? t2 - 56 : t2;
      size_t gbase = ((size_t)bimg * 3136 + ho * 56 + wo) * 384 + c0;
#pragma unroll
      for (int n = 0; n < 2; ++n) {
        size_t gi = gbase + n * 16;
        out[gi] = acc[m][n][e] + bj[n] + xres[gi];
      }
    }
}

// proj GEMM, bf16-residual variant (R12/R17-validated): -> x2b bf16.
__global__ __launch_bounds__(512, 4) void proj_bf16(const u16* __restrict__ A,
                                                    const u16* __restrict__ Bt,
                                                    const float* __restrict__ bias,
                                                    const float* __restrict__ xres,
                                                    u16* __restrict__ x2b) {
  __shared__ char smem[65536];
  int mb, nb;
  xcd_tile(blockIdx.x, 1176, 3, mb, nb);
  f32x4 acc[4][2];
  gemm128w8_core(A, Bt, 384, mb, nb, smem, acc);
  const int lane = threadIdx.x & 63, w = threadIdx.x >> 6;
  const int wr = w >> 2, wc = w & 3;
  const int r0 = mb * 128 + wr * 64 + ((lane >> 4) << 2);
  const int c0 = nb * 128 + wc * 32 + (lane & 15);
  float bj[2];
#pragma unroll
  for (int n = 0; n < 2; ++n) bj[n] = bias[c0 + n * 16];
#pragma unroll
  for (int m = 0; m < 4; ++m)
#pragma unroll
    for (int e = 0; e < 4; ++e) {
      int row = r0 + m * 16 + e;
      int wn = row / 49, tok = row - wn * 49;
      int bimg = wn >> 6, wloc = wn & 63, wi = wloc >> 3, wj = wloc & 7;
      int r = tok / 7, cc = tok - r * 7;
      int t1 = wi * 7 + r + 3;  int ho = t1 >= 56 ? t1 - 56 : t1;
      int t2 = wj * 7 + cc + 3; int wo = t2 >= 56 ? t2 - 56 : t2;
      size_t gbase = ((size_t)bimg * 3136 + ho * 56 + wo) * 384 + c0;
#pragma unroll
      for (int n = 0; n < 2; ++n) {
        size_t gi = gbase + n * 16;
        x2b[gi] = bf16bits(acc[m][n][e] + bj[n] + xres[gi]);
      }
    }
}

// fc1 (128w8 core): [50176,384]x[384,1536] + bias + exact erf GELU -> bf16
__global__ __launch_bounds__(512, 4) void fc1_gemm(const u16* __restrict__ A,
                                                   const u16* __restrict__ Bt,
                                                   const float* __restrict__ bias,
                                                   u16* __restrict__ h3) {
  __shared__ char smem[65536];
  int mb, nb;
  xcd_tile(blockIdx.x, 4704, 12, mb, nb);
  f32x4 acc[4][2];
  gemm128w8_core(A, Bt, 384, mb, nb, smem, acc);
  const int lane = threadIdx.x & 63, w = threadIdx.x >> 6;
  const int wr = w >> 2, wc = w & 3;
  const int r0 = mb * 128 + wr * 64 + ((lane >> 4) << 2);
  const int c0 = nb * 128 + wc * 32 + (lane & 15);
  float bj[2];
#pragma unroll
  for (int n = 0; n < 2; ++n) bj[n] = bias[c0 + n * 16];
#pragma unroll
  for (int m = 0; m < 4; ++m)
#pragma unroll
    for (int e = 0; e < 4; ++e) {
      int row = r0 + m * 16 + e;
      u16* dst = h3 + (size_t)row * 1536 + c0;
#pragma unroll
      for (int n = 0; n < 2; ++n) {
        float v = acc[m][n][e] + bj[n];
        float gl = 0.5f * v * (1.f + erff(v * 0.70710678118654752f));
        dst[n * 16] = bf16bits(gl);
      }
    }
}

// fc2 RMW variant (fallback): out += mlp (out pre-holds x2 f32).
__global__ __launch_bounds__(512, 4) void fc2_rmw(const u16* __restrict__ A,
                                                  const u16* __restrict__ Bt,
                                                  const float* __restrict__ bias,
                                                  float* __restrict__ out) {
  __shared__ char smem[65536];
  int mb, nb;
  xcd_tile(blockIdx.x, 1176, 3, mb, nb);
  f32x4 acc[4][2];
  gemm128w8_core(A, Bt, 1536, mb, nb, smem, acc);
  const int lane = threadIdx.x & 63, w = threadIdx.x >> 6;
  const int wr = w >> 2, wc = w & 3;
  const int r0 = mb * 128 + wr * 64 + ((lane >> 4) << 2);
  const int c0 = nb * 128 + wc * 32 + (lane & 15);
  float bj[2];
#pragma unroll
  for (int n = 0; n < 2; ++n) bj[n] = bias[c0 + n * 16];
#pragma unroll
  for (int m = 0; m < 4; ++m)
#pragma unroll
    for (int e = 0; e < 4; ++e) {
      int row = r0 + m * 16 + e;
      float* dst = out + (size_t)row * 384 + c0;
#pragma unroll
      for (int n = 0; n < 2; ++n)
        dst[n * 16] += acc[m][n][e] + bj[n];
    }
}

// fc2 write-once variant (fast): out = bf16dec(x2b) + mlp.
__global__ __launch_bounds__(512, 4) void fc2_once(const u16* __restrict__ A,
                                                   const u16* __restrict__ Bt,
                                                   const float* __restrict__ bias,
                                                   const u16* __restrict__ x2b,
                                                   float* __restrict__ out) {
  __shared__ char smem[65536];
  int mb, nb;
  xcd_tile(blockIdx.x, 1176, 3, mb, nb);
  f32x4 acc[4][2];
  gemm128w8_core(A, Bt, 1536, mb, nb, smem, acc);
  const int lane = threadIdx.x & 63, w = threadIdx.x >> 6;
  const int wr = w >> 2, wc = w & 3;
  const int r0 = mb * 128 + wr * 64 + ((lane >> 4) << 2);
  const int c0 = nb * 128 + wc * 32 + (lane & 15);
  float bj[2];
#pragma unroll
  for (int n = 0; n < 2; ++n) bj[n] = bias[c0 + n * 16];
#pragma unroll
  for (int m = 0; m < 4; ++m)
#pragma unroll
    for (int e = 0; e < 4; ++e) {
      size_t row = (size_t)(r0 + m * 16 + e);
#pragma unroll
      for (int n = 0; n < 2; ++n) {
        size_t gi = row * 384 + c0 + n * 16;
        out[gi] = bf16dec(x2b[gi]) + acc[m][n][e] + bj[n];
      }
    }
}

// ---------------------------------------------------------------------------
extern "C" void kernel_launch(void* const* d_in, const int* in_sizes, int n_in,
                              void* d_out, int out_size, void* d_ws, size_t ws_size,
                              hipStream_t stream) {
  const float* x      = (const float*)d_in[0];
  const float* n1g    = (const float*)d_in[1];
  const float* n1b    = (const float*)d_in[2];
  const float* qkv_w  = (const float*)d_in[3];
  const float* qkv_b  = (const float*)d_in[4];
  const float* rpb    = (const float*)d_in[5];
  const float* proj_w = (const float*)d_in[6];
  const float* proj_b = (const float*)d_in[7];
  const float* n2g    = (const float*)d_in[8];
  const float* n2b    = (const float*)d_in[9];
  const float* fc1_w  = (const float*)d_in[10];
  const float* fc1_b  = (const float*)d_in[11];
  const float* fc2_w  = (const float*)d_in[12];
  const float* fc2_b  = (const float*)d_in[13];
  float* out = (float*)d_out;

  char* ws = (char*)d_ws;
  const size_t S = (size_t)50176 * 384 * 2;   // 38.5 MB
  const size_t WB = (size_t)(442368 + 147456 + 589824 + 589824) * 2; // weights bytes
  const bool fast = ws_size >= 7 * S + WB + 786432 + (size_t)8 * 1024 * 1024;

  u16* xw = (u16*)ws;                         // [0,S): LN1 out / attn out

  if (fast) {
    // FAST layout (bf16 residual, unchunked):
    // qkvb [S,4S); post-attn: x2b [S,2S), h2 [2S,3S); h3 [3S,7S);
    // bt [7S, +768K); weights after.
    u16* qkvb = (u16*)(ws + S);
    u16* x2b  = (u16*)(ws + S);
    u16* h2   = (u16*)(ws + 2 * S);
    u16* h3   = (u16*)(ws + 3 * S);
    float* bias_t = (float*)(ws + 7 * S);
    u16* wqt  = (u16*)(ws + 7 * S + 786432);
    u16* wpt  = wqt  + 1152 * 384;
    u16* wf1t = wpt  + 384 * 384;
    u16* wf2t = wf1t + 1536 * 384;

    ln1_prep<<<20224, 256, 0, stream>>>(x, n1g, n1b, xw,
                                        qkv_w, proj_w, fc1_w, fc2_w, rpb,
                                        wqt, wpt, wf1t, wf2t, bias_t);
    qkv_gemm<<<3528, 512, 0, stream>>>(xw, wqt, qkv_b, qkvb);
    attn2<<<6144, 128, 0, stream>>>(qkvb, bias_t, xw);
    proj_bf16<<<1176, 512, 0, stream>>>(xw, wpt, proj_b, x, x2b);
    ln2_bf16<<<12544, 256, 0, stream>>>(x2b, n2g, n2b, h2);
    fc1_gemm<<<4704, 512, 0, stream>>>(h2, wf1t, fc1_b, h3);
    fc2_once<<<1176, 512, 0, stream>>>(h3, wf2t, fc2_b, x2b, out);
  } else {
    // FALLBACK = R14 layout (f32 residual in d_out):
    u16* qkvb = (u16*)(ws + S);
    u16* h2   = (u16*)(ws + 4 * S);
    u16* h3   = (u16*)ws;                     // aliases xw+qkvb (dead)
    float* bias_t = (float*)(ws + 4 * S);     // aliases h2 (free until ln2)
    u16* wqt  = (u16*)(ws + 5 * S);
    u16* wpt  = wqt  + 1152 * 384;
    u16* wf1t = wpt  + 384 * 384;
    u16* wf2t = wf1t + 1536 * 384;

    ln1_prep<<<20224, 256, 0, stream>>>(x, n1g, n1b, xw,
                                        qkv_w, proj_w, fc1_w, fc2_w, rpb,
                                        wqt, wpt, wf1t, wf2t, bias_t);
    qkv_gemm<<<3528, 512, 0, stream>>>(xw, wqt, qkv_b, qkvb);
    attn2<<<6144, 128, 0, stream>>>(qkvb, bias_t, xw);
    proj_f32<<<1176, 512, 0, stream>>>(xw, wpt, proj_b, x, out);
    ln2_f32<<<12544, 256, 0, stream>>>(out, n2g, n2b, h2);
    fc1_gemm<<<4704, 512, 0, stream>>>(h2, wf1t, fc1_b, h3);
    fc2_rmw<<<1176, 512, 0, stream>>>(h3, wf2t, fc2_b, out);
  }
}